// Round 4
// baseline (133.441 us; speedup 1.0000x reference)
//
#include <hip/hip_runtime.h>
#include <math.h>

#define HW 256
#define MINNORM 1.17549435e-38f   // 2^-126, f32 min normal

// One wave (64 lanes) per batch element; lane l owns count-support j = l.
// Theory: np ref = XLA-CPU f32 with FTZ/DAZ + exp-underflow-clamped pow:
//   - cd0[j] = 0 exactly for j >= 42 (42*ln p = -89.33 < ln 2^-126 = -87.34)
//   - every product that would be f32-denormal flushes to exact 0
// Support therefore lives in [0, 41] forever -> 64 lanes suffice.

__global__ void __launch_bounds__(64)
spair_count_kl(const float* __restrict__ z_pres,
               const float* __restrict__ z_prob,
               float* __restrict__ out) {
    const int lane = threadIdx.x;   // 0..63
    const int b = blockIdx.x;       // batch element

    // ---- cd0 init: f32 values, FTZ world (no denormals anywhere) ----
    const float e2f = (float)exp(2.0);                    // f32(exp(2))
    const float pf  = (float)(1.0 / ((double)e2f + 1.0)); // p in f32
    const double pd = (double)pf;
    const double l2p = log2(pd);
    // p^j for j<=41 is normal f32; j>=42 underflow-clamps/flushes to 0.
    float cd = 0.0f;
    if (lane <= 41) {
        const double powj = exp2((double)lane * l2p);      // accurate p^j
        float v = (float)((1.0 - pd) * powj);              // (1-p)*p^j, f32
        cd = (v < MINNORM) ? 0.0f : v;                     // FTZ (j=41 = 1.006*2^-126, survives)
    }

    // normalize: cd0 / sum (all terms normal or exact 0)
    {
        float s = cd;
#pragma unroll
        for (int off = 32; off > 0; off >>= 1) s += __shfl_xor(s, off, 64);
        cd = cd / s;
    }

    const float jf = (float)lane;
    float csf = 0.0f;

    const float* presb = z_pres + (size_t)b * HW;
    const float* probb = z_prob + (size_t)b * HW;
    float* outb = out + (size_t)b * HW;

#pragma unroll 1
    for (int k = 0; k < 4; ++k) {
        const float myprob = probb[k * 64 + lane];
        const float mypres = presb[k * 64 + lane];
        // sample = round(z_pres) in {0,1}; rintf = round-half-even = np.round
        const unsigned long long smask = __ballot(rintf(mypres) != 0.0f);
        float my_pz = 0.0f;

#pragma unroll 1
        for (int ii = 0; ii < 64; ++ii) {
            const int i = k * 64 + ii;
            const float fden = (float)(HW - i);
            const bool s1 = ((smask >> ii) & 1ULL) != 0ULL;   // wave-uniform

            // pg = clip(j - csf, 0, den)/den; endpoints exact (0 and 1)
            float t = fminf(fmaxf(jf - csf, 0.0f), fden);
            float pg = t / fden;
            float mult = s1 ? pg : (1.0f - pg);   // exact 0/1 selection

            // individually-rounded products with software FTZ (values >= 0)
            float p1 = cd * pg;
            p1 = (p1 < MINNORM) ? 0.0f : p1;      // flush would-be denormal
            float prodm = cd * mult;
            prodm = (prodm < MINNORM) ? 0.0f : prodm;

            float p2 = prodm;
#pragma unroll
            for (int off = 32; off > 0; off >>= 1) {
                p1 += __shfl_xor(p1, off, 64);
                p2 += __shfl_xor(p2, off, 64);
            }

            float norm = fmaxf(p2, 1e-6f);   // clip(sum, 1e-6, None)
            cd = prodm / norm;               // norm <= ~1: never denormalizes
            csf += s1 ? 1.0f : 0.0f;

            my_pz = (ii == lane) ? p1 : my_pz;   // wave-uniform p_z for step i
        }

        // KL for this lane's step (i = k*64 + lane)
        const float prob = myprob;
        const float pz = my_pz;
        const float kl = prob * (logf(prob + 1e-9f) - logf(pz + 1e-9f))
                       + (1.0f - prob) * (logf((1.0f - prob) + 1e-9f)
                                        - logf((1.0f - pz) + 1e-9f));
        outb[k * 64 + lane] = kl;   // coalesced across the wave
    }
}

extern "C" void kernel_launch(void* const* d_in, const int* in_sizes, int n_in,
                              void* d_out, int out_size, void* d_ws, size_t ws_size,
                              hipStream_t stream) {
    const float* z_pres = (const float*)d_in[0];      // setup_inputs order
    const float* z_prob = (const float*)d_in[1];
    float* out = (float*)d_out;
    const int nbatch = in_sizes[0] / HW;              // 1024
    spair_count_kl<<<dim3(nbatch), dim3(64), 0, stream>>>(z_pres, z_prob, out);
}

// Round 6
// 91.028 us; speedup vs baseline: 1.4659x; 1.4659x over previous
//
#include <hip/hip_runtime.h>
#include <math.h>

#define HW 256
#define MINNORM 1.17549435e-38f   // 2^-126, f32 min normal

// One wave (64 lanes) per batch element; lane l owns count-support j = l.
// np ref semantics (verified R4): XLA-CPU f32, FTZ/DAZ, pow underflow at j=42.
// Support lives in [0,41] forever -> 64 lanes suffice.
// R6: wave reduction = 4x DPP row_shr (CDNA-legal; row_bcast is NOT — R5 fault)
//     + v_readlane cross-row combine. No LDS-pipe ops on the recurrence chain.

template <int CTRL>
__device__ __forceinline__ float dpp_sra(float x) {
    // x + (x shifted toward higher lanes within each row of 16); OOB lanes add 0
    int s = __builtin_amdgcn_update_dpp(0, __builtin_bit_cast(int, x),
                                        CTRL, 0xf, 0xf, true);
    return x + __builtin_bit_cast(float, s);
}

__device__ __forceinline__ float rowsum16(float x) {
    x = dpp_sra<0x111>(x);   // row_shr:1
    x = dpp_sra<0x112>(x);   // row_shr:2
    x = dpp_sra<0x114>(x);   // row_shr:4
    x = dpp_sra<0x118>(x);   // row_shr:8
    return x;                // lane 15 of each row-of-16 holds the row sum
}

__device__ __forceinline__ float rdlane(float x, int lane) {
    return __builtin_bit_cast(float,
        __builtin_amdgcn_readlane(__builtin_bit_cast(int, x), lane));
}

__device__ __forceinline__ float wave_total(float x) {
    const float r = rowsum16(x);
    const float a = rdlane(r, 15), b = rdlane(r, 31);
    const float c = rdlane(r, 47), d = rdlane(r, 63);
    return (a + b) + (c + d);   // nonneg terms: order only ulp-noise
}

__global__ void __launch_bounds__(64)
spair_count_kl(const float* __restrict__ z_pres,
               const float* __restrict__ z_prob,
               float* __restrict__ out) {
    const int lane = threadIdx.x;   // 0..63
    const int b = blockIdx.x;       // batch element

    // ---- cd0 init: f32 values, FTZ world (unchanged from passing R4) ----
    const float e2f = (float)exp(2.0);                    // f32(exp(2))
    const float pf  = (float)(1.0 / ((double)e2f + 1.0)); // p in f32
    const double pd = (double)pf;
    const double l2p = log2(pd);
    float cd = 0.0f;
    if (lane <= 41) {
        const double powj = exp2((double)lane * l2p);      // accurate p^j
        float v = (float)((1.0 - pd) * powj);              // (1-p)*p^j, f32
        cd = (v < MINNORM) ? 0.0f : v;                     // FTZ (j=41 survives)
    }
    {
        float s = cd;
#pragma unroll
        for (int off = 32; off > 0; off >>= 1) s += __shfl_xor(s, off, 64);
        cd = cd / s;
    }

    const float jf = (float)lane;
    float csf = 0.0f;

    const float* presb = z_pres + (size_t)b * HW;
    const float* probb = z_prob + (size_t)b * HW;
    float* outb = out + (size_t)b * HW;

#pragma unroll 1
    for (int k = 0; k < 4; ++k) {
        const float myprob = probb[k * 64 + lane];
        const float mypres = presb[k * 64 + lane];
        // sample = round(z_pres) in {0,1}; rintf = round-half-even = np.round
        const unsigned long long smask = __ballot(rintf(mypres) != 0.0f);
        float my_pz = 0.0f;

#pragma unroll 4
        for (int ii = 0; ii < 64; ++ii) {
            const int i = k * 64 + ii;
            const float fden = (float)(HW - i);
            const bool s1 = ((smask >> ii) & 1ULL) != 0ULL;   // wave-uniform

            // pg = clip(j - csf, 0, den)/den; endpoints exact (0 and 1).
            // Depends only on the cheap csf chain -> schedules ahead under unroll.
            float t = fminf(fmaxf(jf - csf, 0.0f), fden);
            float pg = t / fden;                  // IEEE f32 divide (off-chain)
            float mult = s1 ? pg : (1.0f - pg);   // exact 0/1 endpoints

            // state product with software FTZ (values >= 0) — on-chain
            float prodm = cd * mult;
            prodm = (prodm < MINNORM) ? 0.0f : prodm;
            // p_z terms: no flush — feeds only log(pz+1e-9), not state
            float p1 = cd * pg;

            const float norm = fmaxf(wave_total(prodm), 1e-6f); // clip(sum,1e-6,∞)
            const float pzs = wave_total(p1);                   // off-chain

            cd = prodm / norm;                    // IEEE f32 divide (on-chain)
            csf += s1 ? 1.0f : 0.0f;

            my_pz = (ii == lane) ? pzs : my_pz;   // wave-uniform p_z for step i
        }

        // KL for this lane's step (i = k*64 + lane)
        const float prob = myprob;
        const float pz = my_pz;
        const float kl = prob * (logf(prob + 1e-9f) - logf(pz + 1e-9f))
                       + (1.0f - prob) * (logf((1.0f - prob) + 1e-9f)
                                        - logf((1.0f - pz) + 1e-9f));
        outb[k * 64 + lane] = kl;   // coalesced across the wave
    }
}

extern "C" void kernel_launch(void* const* d_in, const int* in_sizes, int n_in,
                              void* d_out, int out_size, void* d_ws, size_t ws_size,
                              hipStream_t stream) {
    const float* z_pres = (const float*)d_in[0];      // setup_inputs order
    const float* z_prob = (const float*)d_in[1];
    float* out = (float*)d_out;
    const int nbatch = in_sizes[0] / HW;              // 1024
    spair_count_kl<<<dim3(nbatch), dim3(64), 0, stream>>>(z_pres, z_prob, out);
}